// Round 4
// baseline (894.431 us; speedup 1.0000x reference)
//
#include <hip/hip_runtime.h>

// RegressorHybrid: per-edge 2x MLP (128->64->64->32->1, lrelu 0.01), E=2M, H=64.
// Round 4: L2-locality bucketing. Edges sorted into 64 buckets by
// (src/6250, dst/6250); stripe s = blocks with blockIdx%8==s processes buckets
// with dst-chunk s (XCD-pinned dst rows; rotating 800KB src chunks) so gathers
// hit the 4MB per-XCD L2 instead of re-filling from fabric (~3.6TB/s ceiling
// measured in R2/R3).
// Pipeline: prep_frags x2, prep_nodes (f16 tables), zero64, histo, scan64,
// scatter_edges (LDS-aggregated), edge_mlp_mfma (bucket-striped).
// MFMA layouts: A[m=lane&15][k=(lane>>4)*8+j], B[k=(lane>>4)*8+j][n=lane&15],
//               C/D[row=4*(lane>>4)+reg][col=lane&15].

typedef _Float16 half8  __attribute__((ext_vector_type(8)));
typedef _Float16 half4v __attribute__((ext_vector_type(4)));
typedef float    float4v __attribute__((ext_vector_type(4)));

#define LDS_PER_MLP 28672          // w1f 16384 + w2f 8192 + w3f 4096
#define LDS_TOTAL   57344
#define REST_PER_MLP 12288         // w4f 2048 + b1f 4096 + b2f 4096 + b3f 2048
#define W1F 0
#define W2F 16384
#define W3F 24576
#define RW4F 0
#define RB1F 2048
#define RB2F 6144
#define RB3F 10240
#define WS_REST_OFF 57344
#define WS_X16_OFF  81920
#define SCAT_T 131072              // 512 blocks x 256 threads
#define NWS 256                    // waves per stripe (64 blocks x 4 waves)

__device__ __forceinline__ float lrelu(float x) { return fmaxf(x, 0.01f * x); }

__device__ __forceinline__ int uperm(int k) {
    return 16 * (2 * ((k >> 2) & 1) + ((k >> 5) & 1)) + 4 * ((k >> 3) & 3) + (k & 3);
}

// ---- pack one MLP's weights/biases into per-lane fragment order ----
__global__ void prep_frags(const float* __restrict__ w1, const float* __restrict__ b1,
                           const float* __restrict__ w2, const float* __restrict__ b2,
                           const float* __restrict__ w3, const float* __restrict__ b3,
                           const float* __restrict__ w4,
                           unsigned char* __restrict__ dstL,
                           unsigned char* __restrict__ dstR)
{
    int idx = blockIdx.x * blockDim.x + threadIdx.x;
    if (idx < 8192) {                      // w1f: [16 frags][64 lanes][8 f16]
        int L = (idx >> 3) & 63, j = idx & 7, f = idx >> 9;
        int q = L >> 4, mm = L & 15, t = f >> 2, s = f & 3;
        int k = 32 * s + 8 * q + j;
        ((_Float16*)(dstL + W1F))[idx] = (_Float16)w1[k * 64 + 16 * t + mm];
        return;
    }
    idx -= 8192;
    if (idx < 4096) {                      // w2f: [8][64][8]
        int L = (idx >> 3) & 63, j = idx & 7, f = idx >> 9;
        int q = L >> 4, mm = L & 15, t = f >> 1, s = f & 1;
        int u = uperm(32 * s + 8 * q + j);
        ((_Float16*)(dstL + W2F))[idx] = (_Float16)w2[u * 64 + 16 * t + mm];
        return;
    }
    idx -= 4096;
    if (idx < 2048) {                      // w3f: [4][64][8]
        int L = (idx >> 3) & 63, j = idx & 7, f = idx >> 9;
        int q = L >> 4, mm = L & 15, t = f >> 1, s = f & 1;
        int u = uperm(32 * s + 8 * q + j);
        ((_Float16*)(dstL + W3F))[idx] = (_Float16)w3[u * 32 + 16 * t + mm];
        return;
    }
    idx -= 2048;
    if (idx < 512) {                       // w4f
        int L = idx >> 3, j = idx & 7;
        int q = L >> 4, t = j >> 2, r = j & 3;
        ((float*)(dstR + RW4F))[idx] = w4[16 * t + 4 * q + r];
        return;
    }
    idx -= 512;
    if (idx < 1024) {                      // b1f
        int t = idx >> 8, L = (idx >> 2) & 63, r = idx & 3, q = L >> 4;
        ((float*)(dstR + RB1F))[idx] = b1[16 * t + 4 * q + r];
        return;
    }
    idx -= 1024;
    if (idx < 1024) {                      // b2f
        int t = idx >> 8, L = (idx >> 2) & 63, r = idx & 3, q = L >> 4;
        ((float*)(dstR + RB2F))[idx] = b2[16 * t + 4 * q + r];
        return;
    }
    idx -= 1024;
    if (idx < 512) {                       // b3f
        int t = idx >> 8, L = (idx >> 2) & 63, r = idx & 3, q = L >> 4;
        ((float*)(dstR + RB3F))[idx] = b3[16 * t + 4 * q + r];
        return;
    }
}

// ---- convert node tables fp32 -> f16 ----
__global__ void prep_nodes(const float* __restrict__ xs, const float* __restrict__ xd,
                           _Float16* __restrict__ os, _Float16* __restrict__ od, int n4)
{
    int stride = gridDim.x * blockDim.x;
    for (int i = blockIdx.x * blockDim.x + threadIdx.x; i < n4; i += stride) {
        float4v a = ((const float4v*)xs)[i];
        float4v b = ((const float4v*)xd)[i];
        half4v ha, hb;
#pragma unroll
        for (int j = 0; j < 4; ++j) { ha[j] = (_Float16)a[j]; hb[j] = (_Float16)b[j]; }
        ((half4v*)os)[i] = ha;
        ((half4v*)od)[i] = hb;
    }
}

// ---- bucketing: 64 buckets = (src_chunk<<3)|dst_chunk ----
__device__ __forceinline__ int bucket_of(int s, int d, float bscale) {
    int cs = (int)(s * bscale); cs = cs > 7 ? 7 : cs;
    int cd = (int)(d * bscale); cd = cd > 7 ? 7 : cd;
    return (cs << 3) | cd;
}

__global__ void zero64(int* __restrict__ hist) { hist[threadIdx.x] = 0; }

__global__ __launch_bounds__(256)
void histo_edges(const int* __restrict__ eidx, int nE, float bscale,
                 int* __restrict__ hist)
{
    __shared__ int lh[64];
    if (threadIdx.x < 64) lh[threadIdx.x] = 0;
    __syncthreads();
    int tid = blockIdx.x * 256 + threadIdx.x;
#pragma unroll 1
    for (int k = 0; k < 16; ++k) {
        int e = tid + k * SCAT_T;
        if (e < nE) {
            int s = eidx[e], d = eidx[nE + e];
            atomicAdd(&lh[bucket_of(s, d, bscale)], 1);
        }
    }
    __syncthreads();
    if (threadIdx.x < 64) atomicAdd(&hist[threadIdx.x], lh[threadIdx.x]);
}

__global__ void scan64(const int* __restrict__ hist, int* __restrict__ off,
                       int* __restrict__ gcnt)
{
    if (threadIdx.x == 0) {
        int acc = 0;
        for (int i = 0; i < 64; ++i) { off[i] = acc; gcnt[i] = acc; acc += hist[i]; }
        off[64] = acc;
    }
}

__global__ __launch_bounds__(256)
void scatter_edges(const int* __restrict__ eidx, int nE, float bscale,
                   int* __restrict__ gcnt, int2* __restrict__ sorted)
{
    __shared__ int lh[64];
    __shared__ int lbase[64];
    int t = threadIdx.x;
    if (t < 64) lh[t] = 0;
    __syncthreads();
    int tid = blockIdx.x * 256 + t;
    int sdv[16], lpv[16];
#pragma unroll 1
    for (int k = 0; k < 16; ++k) {
        int e = tid + k * SCAT_T;
        if (e < nE) {
            int s = eidx[e], d = eidx[nE + e];
            sdv[k] = s | (d << 16);
            lpv[k] = atomicAdd(&lh[bucket_of(s, d, bscale)], 1);
        }
    }
    __syncthreads();
    if (t < 64) lbase[t] = atomicAdd(&gcnt[t], lh[t]);
    __syncthreads();
#pragma unroll 1
    for (int k = 0; k < 16; ++k) {
        int e = tid + k * SCAT_T;
        if (e < nE) {
            int s = sdv[k] & 0xffff, d = ((unsigned)sdv[k]) >> 16;
            int2 v; v.x = sdv[k]; v.y = e;
            sorted[lbase[bucket_of(s, d, bscale)] + lpv[k]] = v;
        }
    }
}

__device__ __forceinline__ half8 repack2(float4v lo, float4v hi) {
    half8 r;
#pragma unroll
    for (int j = 0; j < 4; ++j) r[j] = (_Float16)lrelu(lo[j]);
#pragma unroll
    for (int j = 0; j < 4; ++j) r[4 + j] = (_Float16)lrelu(hi[j]);
    return r;
}

__device__ __forceinline__ void gather_rows(const _Float16* __restrict__ xs,
                                            const _Float16* __restrict__ xd,
                                            int s, int d, int c4, int4* G)
{
    const char* rs = (const char*)(xs + (size_t)s * 64);
    const char* rd = (const char*)(xd + (size_t)d * 64);
    G[0] = *(const int4*)(rs + 16 * c4);
    G[1] = *(const int4*)(rs + 64 + 16 * c4);
    G[2] = *(const int4*)(rd + 16 * c4);
    G[3] = *(const int4*)(rd + 64 + 16 * c4);
}

__device__ __forceinline__ half8 bperm16(int bpidx, int4 g) {
    int4 r;
    r.x = __builtin_amdgcn_ds_bpermute(bpidx, g.x);
    r.y = __builtin_amdgcn_ds_bpermute(bpidx, g.y);
    r.z = __builtin_amdgcn_ds_bpermute(bpidx, g.z);
    r.w = __builtin_amdgcn_ds_bpermute(bpidx, g.w);
    return __builtin_bit_cast(half8, r);
}

__global__ __launch_bounds__(256, 2)
void edge_mlp_mfma(const unsigned char* __restrict__ ws,
                   const _Float16* __restrict__ xs, const _Float16* __restrict__ xd,
                   const int* __restrict__ offp, const int2* __restrict__ sorted,
                   const float* __restrict__ eb4p, const float* __restrict__ wb4p,
                   float* __restrict__ out, int nE)
{
    __shared__ unsigned char lds[LDS_TOTAL];
    {
        const uint4* s = (const uint4*)ws;
        uint4* d = (uint4*)lds;
        for (int i = threadIdx.x; i < LDS_TOTAL / 16; i += 256) d[i] = s[i];
    }
    __syncthreads();

    const int lane = threadIdx.x & 63;
    const int q = lane >> 4, n = lane & 15;
    const int el = lane >> 2, c4 = lane & 3;
    const int bpidx = ((((lane & 15) << 2) | (lane >> 4)) << 2);
    const int stripe = blockIdx.x & 7;                     // == dst chunk == XCD (heuristic)
    const int wslot = ((blockIdx.x >> 3) << 2) | (threadIdx.x >> 6);  // 0..255

    // hoist bias / w4 fragments
    float4v b1v[2][4], b2v[2][4], b3v[2][2], w4v[2][2];
    float b4s[2];
    const float* b4p[2] = { eb4p, wb4p };
#pragma unroll
    for (int m = 0; m < 2; ++m) {
        const unsigned char* rb = ws + WS_REST_OFF + m * REST_PER_MLP;
#pragma unroll
        for (int t = 0; t < 4; ++t) b1v[m][t] = *(const float4v*)(rb + RB1F + (t * 64 + lane) * 16);
#pragma unroll
        for (int t = 0; t < 4; ++t) b2v[m][t] = *(const float4v*)(rb + RB2F + (t * 64 + lane) * 16);
#pragma unroll
        for (int t = 0; t < 2; ++t) b3v[m][t] = *(const float4v*)(rb + RB3F + (t * 64 + lane) * 16);
        w4v[m][0] = *(const float4v*)(rb + RW4F + lane * 32);
        w4v[m][1] = *(const float4v*)(rb + RW4F + lane * 32 + 16);
        b4s[m] = b4p[m][0];
    }

#pragma unroll 1
    for (int ii = 0; ii < 8; ++ii) {
        const int b = ((((ii + stripe) & 7) << 3) | stripe);   // staggered src chunks
        const int beg = offp[b], end = offp[b + 1];
        if (end <= beg) continue;
        const int nt = (end - beg + 15) >> 4;
        int t = wslot;
        if (t >= nt) continue;

        int4 Gc[4], Gn[4];
        {
            int ee = beg + (t << 4) + el; if (ee >= end) ee = end - 1;
            int2 se = sorted[ee];
            gather_rows(xs, xd, se.x & 0xffff, ((unsigned)se.x) >> 16, c4, Gc);
        }
#pragma unroll 1
        for (; t < nt; t += NWS) {
            const int base = beg + (t << 4);
            half8 B1[4];
#pragma unroll
            for (int s = 0; s < 4; ++s) B1[s] = bperm16(bpidx, Gc[s]);

            int tn = t + NWS;
            if (tn < nt) {
                int ee = beg + (tn << 4) + el; if (ee >= end) ee = end - 1;
                int2 se = sorted[ee];
                gather_rows(xs, xd, se.x & 0xffff, ((unsigned)se.x) >> 16, c4, Gn);
            }

            float res[2];
#pragma unroll
            for (int m = 0; m < 2; ++m) {
                const unsigned char* mb = lds + m * LDS_PER_MLP;
                float4v acc[4];
#pragma unroll
                for (int tt = 0; tt < 4; ++tt) {
                    acc[tt] = b1v[m][tt];
#pragma unroll
                    for (int s = 0; s < 4; ++s) {
                        half8 A = *(const half8*)(mb + W1F + ((tt * 4 + s) * 64 + lane) * 16);
                        acc[tt] = __builtin_amdgcn_mfma_f32_16x16x32_f16(A, B1[s], acc[tt], 0, 0, 0);
                    }
                }
                half8 B2[2] = { repack2(acc[0], acc[2]), repack2(acc[1], acc[3]) };
                float4v acc2[4];
#pragma unroll
                for (int tt = 0; tt < 4; ++tt) {
                    acc2[tt] = b2v[m][tt];
#pragma unroll
                    for (int s = 0; s < 2; ++s) {
                        half8 A = *(const half8*)(mb + W2F + ((tt * 2 + s) * 64 + lane) * 16);
                        acc2[tt] = __builtin_amdgcn_mfma_f32_16x16x32_f16(A, B2[s], acc2[tt], 0, 0, 0);
                    }
                }
                half8 B3[2] = { repack2(acc2[0], acc2[2]), repack2(acc2[1], acc2[3]) };
                float4v acc3[2];
#pragma unroll
                for (int tt = 0; tt < 2; ++tt) {
                    acc3[tt] = b3v[m][tt];
#pragma unroll
                    for (int s = 0; s < 2; ++s) {
                        half8 A = *(const half8*)(mb + W3F + ((tt * 2 + s) * 64 + lane) * 16);
                        acc3[tt] = __builtin_amdgcn_mfma_f32_16x16x32_f16(A, B3[s], acc3[tt], 0, 0, 0);
                    }
                }
                float o = 0.f;
#pragma unroll
                for (int r = 0; r < 4; ++r) o = fmaf(lrelu(acc3[0][r]), w4v[m][0][r], o);
#pragma unroll
                for (int r = 0; r < 4; ++r) o = fmaf(lrelu(acc3[1][r]), w4v[m][1][r], o);
                o += __shfl_xor(o, 16, 64);
                o += __shfl_xor(o, 32, 64);
                res[m] = o + b4s[m];
            }

            int een = base + n;
            bool valid = een < end;
            if (!valid) een = end - 1;
            int eo = sorted[een].y;
            if (q == 0 && valid) {
                out[eo] = res[0];
                out[nE + eo] = res[1];
            }
#pragma unroll
            for (int s = 0; s < 4; ++s) Gc[s] = Gn[s];
        }
    }
}

extern "C" void kernel_launch(void* const* d_in, const int* in_sizes, int n_in,
                              void* d_out, int out_size, void* d_ws, size_t ws_size,
                              hipStream_t stream)
{
    const float* x_src = (const float*)d_in[0];
    const float* x_dst = (const float*)d_in[1];
    const int*   eidx  = (const int*)d_in[2];
    const float* ew1 = (const float*)d_in[3];
    const float* eb1 = (const float*)d_in[4];
    const float* ww1 = (const float*)d_in[5];
    const float* wb1 = (const float*)d_in[6];
    const float* ew2 = (const float*)d_in[7];
    const float* eb2 = (const float*)d_in[8];
    const float* ww2 = (const float*)d_in[9];
    const float* wb2 = (const float*)d_in[10];
    const float* ew3 = (const float*)d_in[11];
    const float* eb3 = (const float*)d_in[12];
    const float* ww3 = (const float*)d_in[13];
    const float* wb3 = (const float*)d_in[14];
    const float* ew4 = (const float*)d_in[15];
    const float* eb4 = (const float*)d_in[16];
    const float* ww4 = (const float*)d_in[17];
    const float* wb4 = (const float*)d_in[18];
    float* out = (float*)d_out;

    const int nE = in_sizes[2] / 2;
    const int nNodeElems = in_sizes[0];          // nNodes * 64
    const int nNodes = nNodeElems / 64;
    const float bscale = 8.0f / (float)nNodes;

    unsigned char* ws = (unsigned char*)d_ws;
    _Float16* xs16 = (_Float16*)(ws + WS_X16_OFF);
    _Float16* xd16 = xs16 + nNodeElems;

    size_t hist_off = ((size_t)WS_X16_OFF + (size_t)4 * nNodeElems + 255) & ~(size_t)255;
    int*  hist   = (int*)(ws + hist_off);
    int*  offp   = (int*)(ws + hist_off + 256);
    int*  gcnt   = (int*)(ws + hist_off + 768);
    int2* sorted = (int2*)(ws + hist_off + 1024);

    prep_frags<<<68, 256, 0, stream>>>(ew1, eb1, ew2, eb2, ew3, eb3, ew4,
                                       ws, ws + WS_REST_OFF);
    prep_frags<<<68, 256, 0, stream>>>(ww1, wb1, ww2, wb2, ww3, wb3, ww4,
                                       ws + LDS_PER_MLP, ws + WS_REST_OFF + REST_PER_MLP);
    prep_nodes<<<1024, 256, 0, stream>>>(x_src, x_dst, xs16, xd16, nNodeElems / 4);
    zero64<<<1, 64, 0, stream>>>(hist);
    histo_edges<<<512, 256, 0, stream>>>(eidx, nE, bscale, hist);
    scan64<<<1, 64, 0, stream>>>(hist, offp, gcnt);
    scatter_edges<<<512, 256, 0, stream>>>(eidx, nE, bscale, gcnt, sorted);
    edge_mlp_mfma<<<512, 256, 0, stream>>>(ws, xs16, xd16, offp, sorted,
                                           eb4, wb4, out, nE);
}